// Round 1
// baseline (528.654 us; speedup 1.0000x reference)
//
#include <hip/hip_runtime.h>
#include <cstdint>
#include <cstddef>

// ---- dims (fixed for this problem) ----
#define SEQ   256      // n_seq
#define LDIM  256      // L
#define CM    256
#define CZ    128
#define NHEAD 8
#define CH    32
#define ROWS  (SEQ*LDIM)   // 65536

using bfrag8 = __attribute__((ext_vector_type(8))) short;  // 8 bf16 = 4 VGPR
using facc4  = __attribute__((ext_vector_type(4))) float;  // MFMA accumulator

__device__ __forceinline__ unsigned short f2bf(float f){
  unsigned int u = __builtin_bit_cast(unsigned int, f);
  u += 0x7fffu + ((u >> 16) & 1u);          // RNE
  return (unsigned short)(u >> 16);
}
__device__ __forceinline__ float bf2f(unsigned short h){
  unsigned int u = ((unsigned int)h) << 16;
  return __builtin_bit_cast(float, u);
}
__device__ __forceinline__ facc4 mm16(bfrag8 a, bfrag8 b, facc4 c){
  return __builtin_amdgcn_mfma_f32_16x16x32_bf16(a, b, c, 0, 0, 0);
}

// =====================================================================
// k_prep: W[k][n] fp32 -> WT[w][n][k] bf16 for Wq,Wk,Wv,Wg,Wo
// grid 5*256, block 256
// =====================================================================
__global__ __launch_bounds__(256) void kp_prep(
    const float* __restrict__ Wq, const float* __restrict__ Wk,
    const float* __restrict__ Wv, const float* __restrict__ Wg,
    const float* __restrict__ Wo, unsigned short* __restrict__ WT){
  int b = blockIdx.x;
  int w = b >> 8;          // which weight
  int k = b & 255;         // source row
  int n = threadIdx.x;     // source col
  const float* W = (w==0)?Wq:(w==1)?Wk:(w==2)?Wv:(w==3)?Wg:Wo;
  WT[w*65536 + n*256 + k] = f2bf(W[k*256 + n]);
}

// =====================================================================
// k_proj: LN(m) then 4 projections. grid 1024 (64 rows each), block 256.
//  q,k,v -> [l][h][s][c] bf16 ; g -> sigmoid(.+bg) [row][n] bf16
// =====================================================================
__global__ __launch_bounds__(256) void kp_proj(
    const float* __restrict__ m, const float* __restrict__ g_m,
    const float* __restrict__ b_m, const unsigned short* __restrict__ WT,
    const float* __restrict__ bg,
    unsigned short* __restrict__ qws, unsigned short* __restrict__ kws,
    unsigned short* __restrict__ vws, unsigned short* __restrict__ gws){
  __shared__ unsigned short Mt[64*256];   // bf16 LN tile, XOR-swizzled 16B chunks
  int tid = threadIdx.x;
  int r0  = blockIdx.x * 64;

  // ---- LN staging: 4 threads per row, 64 elems each ----
  {
    int rw = tid >> 2, part = tid & 3;
    int grow = r0 + rw;
    const float* mrow = m + (size_t)grow*256 + part*64;
    float x[64];
    float s1 = 0.f, s2 = 0.f;
#pragma unroll
    for (int j = 0; j < 16; j++){
      float4 v = reinterpret_cast<const float4*>(mrow)[j];
      x[j*4+0]=v.x; x[j*4+1]=v.y; x[j*4+2]=v.z; x[j*4+3]=v.w;
      s1 += v.x+v.y+v.z+v.w;
      s2 += v.x*v.x+v.y*v.y+v.z*v.z+v.w*v.w;
    }
    s1 += __shfl_xor(s1,1); s1 += __shfl_xor(s1,2);
    s2 += __shfl_xor(s2,1); s2 += __shfl_xor(s2,2);
    float mu = s1*(1.f/256.f);
    float var = s2*(1.f/256.f) - mu*mu;
    float rs = rsqrtf(var + 1e-5f);
    const float* gmp = g_m + part*64;
    const float* bmp = b_m + part*64;
#pragma unroll
    for (int c8 = 0; c8 < 8; c8++){
      bfrag8 st;
#pragma unroll
      for (int e = 0; e < 8; e++){
        int kk = c8*8+e;
        float y = (x[kk]-mu)*rs*gmp[kk] + bmp[kk];
        st[e] = (short)f2bf(y);
      }
      int c = part*8 + c8;                      // logical 16B chunk (0..31)
      *reinterpret_cast<bfrag8*>(&Mt[rw*256 + ((c ^ (rw & 7)) << 3)]) = st;
    }
  }
  __syncthreads();

  // ---- GEMM: each wave -> 64 rows x 64 cols per weight ----
  int w = tid >> 6, lane = tid & 63, i = lane & 15, g = lane >> 4;
#pragma unroll 1
  for (int wi = 0; wi < 4; wi++){
    const unsigned short* WTw = WT + wi*65536;   // [n][k] bf16
    facc4 acc[4][4];
#pragma unroll
    for (int mt = 0; mt < 4; mt++)
#pragma unroll
      for (int nt = 0; nt < 4; nt++)
        acc[mt][nt] = (facc4){0.f,0.f,0.f,0.f};
#pragma unroll
    for (int ks = 0; ks < 8; ks++){
      bfrag8 a[4];
#pragma unroll
      for (int mt = 0; mt < 4; mt++)
        a[mt] = *reinterpret_cast<const bfrag8*>(
            &Mt[(mt*16+i)*256 + (((ks*4+g) ^ (i & 7)) << 3)]);
#pragma unroll
      for (int nt = 0; nt < 4; nt++){
        int n = w*64 + nt*16 + i;
        bfrag8 b = *reinterpret_cast<const bfrag8*>(WTw + n*256 + ks*32 + g*8);
#pragma unroll
        for (int mt = 0; mt < 4; mt++)
          acc[mt][nt] = mm16(a[mt], b, acc[mt][nt]);
      }
    }
    // ---- epilogue ----
    if (wi < 3){
      unsigned short* dst = (wi==0) ? qws : (wi==1) ? kws : vws;  // [l][h][s][c]
#pragma unroll
      for (int nt = 0; nt < 4; nt++){
        int col = w*64 + nt*16 + i;
        int hh = col >> 5, cc = col & 31;
#pragma unroll
        for (int mt = 0; mt < 4; mt++){
#pragma unroll
          for (int r = 0; r < 4; r++){
            int grow = r0 + mt*16 + 4*g + r;
            int ss = grow >> 8, ll = grow & 255;
            dst[((ll*8+hh)*256 + ss)*32 + cc] = f2bf(acc[mt][nt][r]);
          }
        }
      }
    } else {
#pragma unroll
      for (int nt = 0; nt < 4; nt++){
        int col = w*64 + nt*16 + i;
        float bgv = bg[col];
#pragma unroll
        for (int mt = 0; mt < 4; mt++){
#pragma unroll
          for (int r = 0; r < 4; r++){
            int grow = r0 + mt*16 + 4*g + r;
            float t = acc[mt][nt][r] + bgv;
            float sg = 1.0f / (1.0f + __expf(-t));
            gws[grow*256 + col] = f2bf(sg);
          }
        }
      }
    }
  }
}

// =====================================================================
// k_bias: LN(z) then z_ln @ Wb -> bias[h][i][j] bf16. grid 256, block 256.
// =====================================================================
__global__ __launch_bounds__(256) void kp_bias(
    const float* __restrict__ z, const float* __restrict__ g_z,
    const float* __restrict__ b_z, const float* __restrict__ Wb,
    unsigned short* __restrict__ biasws){
  __shared__ float WbL[128*8];
  __shared__ float gzL[128], bzL[128];
  int tid = threadIdx.x;
  for (int t = tid; t < 1024; t += 256) WbL[t] = Wb[t];
  if (tid < 128){ gzL[tid] = g_z[tid]; bzL[tid] = b_z[tid]; }
  __syncthreads();

  int row = blockIdx.x*256 + tid;
  const float* zr = z + (size_t)row*128;
  float x[128];
  float s1 = 0.f, s2 = 0.f;
#pragma unroll
  for (int j = 0; j < 32; j++){
    float4 v = reinterpret_cast<const float4*>(zr)[j];
    x[j*4+0]=v.x; x[j*4+1]=v.y; x[j*4+2]=v.z; x[j*4+3]=v.w;
    s1 += v.x+v.y+v.z+v.w;
    s2 += v.x*v.x+v.y*v.y+v.z*v.z+v.w*v.w;
  }
  float mu = s1*(1.f/128.f);
  float var = s2*(1.f/128.f) - mu*mu;
  float rs = rsqrtf(var + 1e-5f);
  float acc[8] = {0,0,0,0,0,0,0,0};
#pragma unroll
  for (int zi = 0; zi < 128; zi++){
    float v = (x[zi]-mu)*rs*gzL[zi] + bzL[zi];
    float4 wa = *reinterpret_cast<const float4*>(&WbL[zi*8]);
    float4 wb = *reinterpret_cast<const float4*>(&WbL[zi*8+4]);
    acc[0] += v*wa.x; acc[1] += v*wa.y; acc[2] += v*wa.z; acc[3] += v*wa.w;
    acc[4] += v*wb.x; acc[5] += v*wb.y; acc[6] += v*wb.z; acc[7] += v*wb.w;
  }
#pragma unroll
  for (int h = 0; h < 8; h++)
    biasws[h*65536 + row] = f2bf(acc[h]);
}

// =====================================================================
// k_attn: per-(l,h) flash-free attention (S=256 fits). grid 2048, block 256.
// =====================================================================
__global__ __launch_bounds__(256) void kp_attn(
    const unsigned short* __restrict__ qws, const unsigned short* __restrict__ kws,
    const unsigned short* __restrict__ vws, const unsigned short* __restrict__ biasws,
    unsigned short* __restrict__ ows){
  __shared__ unsigned short Kt[256*32];    // [t][c] swizzled
  __shared__ unsigned short Vt[32*256];    // [c][t] swizzled
  __shared__ unsigned short Pt[4*16*256];  // per-wave P tile, swizzled
  int tid = threadIdx.x;
  int l = blockIdx.x >> 3, h = blockIdx.x & 7;
  int base = (l*8+h)*8192;                 // elements into [l][h][256][32]

  // stage K
#pragma unroll
  for (int it = 0; it < 4; it++){
    int f = tid + it*256;                  // 16B chunk id (0..1023)
    int t = f >> 2, cj = f & 3;
    bfrag8 v = *reinterpret_cast<const bfrag8*>(kws + base + f*8);
    *reinterpret_cast<bfrag8*>(&Kt[t*32 + ((cj ^ ((t>>1)&3)) << 3)]) = v;
  }
  // stage V transposed: [s][c] -> Vt[c][s]
#pragma unroll
  for (int it = 0; it < 4; it++){
    int f = tid + it*256;
    int s = f >> 2, c8 = f & 3;
    bfrag8 v = *reinterpret_cast<const bfrag8*>(vws + base + f*8);
#pragma unroll
    for (int e = 0; e < 8; e++){
      int c = c8*8 + e;
      Vt[c*256 + (((s>>3) ^ (c&7)) << 3) + (s&7)] = (unsigned short)v[e];
    }
  }
  __syncthreads();

  int w = tid >> 6, lane = tid & 63, i = lane & 15, g = lane >> 4;
  const unsigned short* bb = biasws + h*65536;
  unsigned short* Ptw = Pt + w*4096;
  const float scale = 0.17677669529663689f;   // 1/sqrt(32)

  for (int pass = 0; pass < 4; pass++){
    int s0 = (pass*4 + w)*16;
    // Q A-frag straight from global (no reuse)
    bfrag8 aq = *reinterpret_cast<const bfrag8*>(qws + base + (s0+i)*32 + g*8);
    facc4 accs[16];
    facc4 zac = (facc4){0.f,0.f,0.f,0.f};
#pragma unroll
    for (int tt = 0; tt < 16; tt++){
      int t = tt*16 + i;
      bfrag8 bk = *reinterpret_cast<const bfrag8*>(
          &Kt[t*32 + ((g ^ ((t>>1)&3)) << 3)]);
      accs[tt] = mm16(aq, bk, zac);
    }
    // bias + scale, row max
    float rowmax[4] = {-3.0e38f,-3.0e38f,-3.0e38f,-3.0e38f};
#pragma unroll
    for (int tt = 0; tt < 16; tt++){
#pragma unroll
      for (int r = 0; r < 4; r++){
        float bv = bf2f(bb[(s0 + 4*g + r)*256 + tt*16 + i]);
        float fx = accs[tt][r]*scale + bv;
        accs[tt][r] = fx;
        rowmax[r] = fmaxf(rowmax[r], fx);
      }
    }
#pragma unroll
    for (int r = 0; r < 4; r++){
      float v = rowmax[r];
      v = fmaxf(v, __shfl_xor(v,1)); v = fmaxf(v, __shfl_xor(v,2));
      v = fmaxf(v, __shfl_xor(v,4)); v = fmaxf(v, __shfl_xor(v,8));
      rowmax[r] = v;
    }
    float rowsum[4] = {0.f,0.f,0.f,0.f};
#pragma unroll
    for (int tt = 0; tt < 16; tt++){
#pragma unroll
      for (int r = 0; r < 4; r++){
        float p = __expf(accs[tt][r] - rowmax[r]);
        accs[tt][r] = p;
        rowsum[r] += p;
      }
    }
#pragma unroll
    for (int r = 0; r < 4; r++){
      float v = rowsum[r];
      v += __shfl_xor(v,1); v += __shfl_xor(v,2);
      v += __shfl_xor(v,4); v += __shfl_xor(v,8);
      rowsum[r] = v;
    }
    // write P (bf16) to per-wave LDS tile
#pragma unroll
    for (int tt = 0; tt < 16; tt++){
#pragma unroll
      for (int r = 0; r < 4; r++){
        int prow = 4*g + r;
        int col = tt*16 + i;
        int ch = col >> 3;
        Ptw[prow*256 + ((ch ^ (prow&7)) << 3) + (col&7)] = f2bf(accs[tt][r]);
      }
    }
    __syncthreads();
    // PV: O[16][32]
    facc4 acco0 = zac, acco1 = zac;
#pragma unroll
    for (int kt = 0; kt < 8; kt++){
      bfrag8 ap = *reinterpret_cast<const bfrag8*>(
          &Ptw[i*256 + (((kt*4+g) ^ (i&7)) << 3)]);
      bfrag8 b0 = *reinterpret_cast<const bfrag8*>(
          &Vt[i*256 + (((kt*4+g) ^ (i&7)) << 3)]);
      bfrag8 b1 = *reinterpret_cast<const bfrag8*>(
          &Vt[(16+i)*256 + (((kt*4+g) ^ (i&7)) << 3)]);
      acco0 = mm16(ap, b0, acco0);
      acco1 = mm16(ap, b1, acco1);
    }
#pragma unroll
    for (int r = 0; r < 4; r++){
      float inv = 1.0f / rowsum[r];
      int s = s0 + 4*g + r;
      int ob = (s*256 + l)*256 + h*32;
      ows[ob + i]      = f2bf(acco0[r]*inv);
      ows[ob + 16 + i] = f2bf(acco1[r]*inv);
    }
    __syncthreads();   // protect Pt before next pass
  }
}

// =====================================================================
// k_out: out = (g .* o) @ Wo + bo. grid 1024, block 256.
// =====================================================================
__global__ __launch_bounds__(256) void kp_out(
    const unsigned short* __restrict__ gws, const unsigned short* __restrict__ ows,
    const unsigned short* __restrict__ WT, const float* __restrict__ bo,
    float* __restrict__ out){
  __shared__ unsigned short Mt[64*256];
  int tid = threadIdx.x;
  int r0  = blockIdx.x * 64;
  {
    int rw = tid >> 2, part = tid & 3;
    int grow = r0 + rw;
    const unsigned short* gp = gws + (size_t)grow*256 + part*64;
    const unsigned short* op = ows + (size_t)grow*256 + part*64;
#pragma unroll
    for (int c8 = 0; c8 < 8; c8++){
      bfrag8 gv = *reinterpret_cast<const bfrag8*>(gp + c8*8);
      bfrag8 ov = *reinterpret_cast<const bfrag8*>(op + c8*8);
      bfrag8 st;
#pragma unroll
      for (int e = 0; e < 8; e++){
        float y = bf2f((unsigned short)gv[e]) * bf2f((unsigned short)ov[e]);
        st[e] = (short)f2bf(y);
      }
      int c = part*8 + c8;
      *reinterpret_cast<bfrag8*>(&Mt[rw*256 + ((c ^ (rw & 7)) << 3)]) = st;
    }
  }
  __syncthreads();

  int w = tid >> 6, lane = tid & 63, i = lane & 15, g = lane >> 4;
  const unsigned short* WTw = WT + 4*65536;   // Wo^T
  facc4 acc[4][4];
#pragma unroll
  for (int mt = 0; mt < 4; mt++)
#pragma unroll
    for (int nt = 0; nt < 4; nt++)
      acc[mt][nt] = (facc4){0.f,0.f,0.f,0.f};
#pragma unroll
  for (int ks = 0; ks < 8; ks++){
    bfrag8 a[4];
#pragma unroll
    for (int mt = 0; mt < 4; mt++)
      a[mt] = *reinterpret_cast<const bfrag8*>(
          &Mt[(mt*16+i)*256 + (((ks*4+g) ^ (i & 7)) << 3)]);
#pragma unroll
    for (int nt = 0; nt < 4; nt++){
      int n = w*64 + nt*16 + i;
      bfrag8 b = *reinterpret_cast<const bfrag8*>(WTw + n*256 + ks*32 + g*8);
#pragma unroll
      for (int mt = 0; mt < 4; mt++)
        acc[mt][nt] = mm16(a[mt], b, acc[mt][nt]);
    }
  }
#pragma unroll
  for (int nt = 0; nt < 4; nt++){
    int col = w*64 + nt*16 + i;
    float bov = bo[col];
#pragma unroll
    for (int mt = 0; mt < 4; mt++){
#pragma unroll
      for (int r = 0; r < 4; r++){
        int grow = r0 + mt*16 + 4*g + r;
        out[(size_t)grow*256 + col] = acc[mt][nt][r] + bov;
      }
    }
  }
}

// =====================================================================
extern "C" void kernel_launch(void* const* d_in, const int* in_sizes, int n_in,
                              void* d_out, int out_size, void* d_ws, size_t ws_size,
                              hipStream_t stream) {
  (void)in_sizes; (void)n_in; (void)out_size; (void)ws_size;
  const float* m   = (const float*)d_in[0];
  const float* z   = (const float*)d_in[1];
  const float* g_m = (const float*)d_in[2];
  const float* b_m = (const float*)d_in[3];
  const float* g_z = (const float*)d_in[4];
  const float* b_z = (const float*)d_in[5];
  const float* Wq  = (const float*)d_in[6];
  const float* Wk  = (const float*)d_in[7];
  const float* Wv  = (const float*)d_in[8];
  const float* Wb  = (const float*)d_in[9];
  const float* Wg  = (const float*)d_in[10];
  const float* bg  = (const float*)d_in[11];
  const float* Wo  = (const float*)d_in[12];
  const float* bo  = (const float*)d_in[13];

  char* ws = (char*)d_ws;
  unsigned short* qws    = (unsigned short*)(ws);                 // 32 MB  [l][h][s][c]
  unsigned short* kws    = (unsigned short*)(ws + 33554432);      // 32 MB  [l][h][s][c]
  unsigned short* vws    = (unsigned short*)(ws + 67108864);      // 32 MB  [l][h][s][c]
  unsigned short* gws    = (unsigned short*)(ws + 100663296);     // 32 MB  [row][n]
  unsigned short* ows    = (unsigned short*)(ws + 134217728);     // 32 MB  [s][l][n]
  unsigned short* biasws = (unsigned short*)(ws + 167772160);     // 1 MB   [h][s][t]
  unsigned short* WT     = (unsigned short*)(ws + 168820736);     // 640 KB [w][n][k]
  float* out = (float*)d_out;

  kp_prep<<<dim3(1280), dim3(256), 0, stream>>>(Wq, Wk, Wv, Wg, Wo, WT);
  kp_proj<<<dim3(1024), dim3(256), 0, stream>>>(m, g_m, b_m, WT, bg, qws, kws, vws, gws);
  kp_bias<<<dim3(256),  dim3(256), 0, stream>>>(z, g_z, b_z, Wb, biasws);
  kp_attn<<<dim3(2048), dim3(256), 0, stream>>>(qws, kws, vws, biasws, ows);
  kp_out <<<dim3(1024), dim3(256), 0, stream>>>(gws, ows, WT, bo, out);
}

// Round 2
// 471.843 us; speedup vs baseline: 1.1204x; 1.1204x over previous
//
#include <hip/hip_runtime.h>
#include <cstdint>
#include <cstddef>

using bfrag8 = __attribute__((ext_vector_type(8))) short;  // 8 bf16
using facc4  = __attribute__((ext_vector_type(4))) float;  // MFMA acc

__device__ __forceinline__ unsigned short f2bf(float f){
  unsigned int u = __builtin_bit_cast(unsigned int, f);
  u += 0x7fffu + ((u >> 16) & 1u);          // RNE
  return (unsigned short)(u >> 16);
}
__device__ __forceinline__ float bf2f(unsigned short h){
  unsigned int u = ((unsigned int)h) << 16;
  return __builtin_bit_cast(float, u);
}
__device__ __forceinline__ unsigned int pk2(float a, float b){
  return (unsigned int)f2bf(a) | ((unsigned int)f2bf(b) << 16);
}
__device__ __forceinline__ facc4 mm16(bfrag8 a, bfrag8 b, facc4 c){
  return __builtin_amdgcn_mfma_f32_16x16x32_bf16(a, b, c, 0, 0, 0);
}

// =====================================================================
// kp_prep: W[k][n] fp32 -> WT[w][n][k] bf16. For Wo (w==4) the K index
// (the H*C channel) is permuted by pi(c)= (c&~31)|((c&15)<<1)|((c>>4)&1)
// to match the phys channel order of gws/ows.
// =====================================================================
__global__ __launch_bounds__(256) void kp_prep(
    const float* __restrict__ Wq, const float* __restrict__ Wk,
    const float* __restrict__ Wv, const float* __restrict__ Wg,
    const float* __restrict__ Wo, unsigned short* __restrict__ WT){
  int b = blockIdx.x;
  int w = b >> 8;          // which weight
  int k = b & 255;         // source row (input dim)
  int n = threadIdx.x;     // source col (output dim)
  const float* W = (w==0)?Wq:(w==1)?Wk:(w==2)?Wv:(w==3)?Wg:Wo;
  int kk = (w == 4) ? ((k & ~31) | ((k & 15) << 1) | ((k >> 4) & 1)) : k;
  WT[w*65536 + n*256 + kk] = f2bf(W[k*256 + n]);
}

// =====================================================================
// kp_proj: LN(m) + 4 projections. Blocks: l fixed, 64 s-rows.
// q,k -> [l][h][s][c_phys] ; v -> [l][h][c][s] (transposed) ;
// g -> sigmoid(.+bg) [row][n_phys].  All stores 16B coalesced via LDS.
// =====================================================================
__global__ __launch_bounds__(256, 4) void kp_proj(
    const float* __restrict__ m, const float* __restrict__ g_m,
    const float* __restrict__ b_m, const unsigned short* __restrict__ WT,
    const float* __restrict__ bg,
    unsigned short* __restrict__ qws, unsigned short* __restrict__ kws,
    unsigned short* __restrict__ vws, unsigned short* __restrict__ gws){
  __shared__ __align__(16) char smem[45056];
  unsigned short* Mt = (unsigned short*)smem;    // 64x256 bf16, swizzled
  int tid = threadIdx.x;
  int l   = blockIdx.x & 255;
  int s0b = (blockIdx.x >> 8) * 64;

  // ---- LN staging: 8 threads/row, 2 iterations of 32 rows ----
  for (int iter = 0; iter < 2; iter++){
    int rw = iter*32 + (tid >> 3);
    int part = tid & 7;
    const float* mrow = m + ((size_t)((s0b + rw)*256 + l))*256 + part*32;
    float x[32];
    float s1 = 0.f, s2 = 0.f;
#pragma unroll
    for (int j = 0; j < 8; j++){
      float4 v = reinterpret_cast<const float4*>(mrow)[j];
      x[j*4+0]=v.x; x[j*4+1]=v.y; x[j*4+2]=v.z; x[j*4+3]=v.w;
      s1 += v.x+v.y+v.z+v.w;
      s2 += v.x*v.x+v.y*v.y+v.z*v.z+v.w*v.w;
    }
    s1 += __shfl_xor(s1,1); s1 += __shfl_xor(s1,2); s1 += __shfl_xor(s1,4);
    s2 += __shfl_xor(s2,1); s2 += __shfl_xor(s2,2); s2 += __shfl_xor(s2,4);
    float mu = s1*(1.f/256.f);
    float var = s2*(1.f/256.f) - mu*mu;
    float rs = rsqrtf(var + 1e-5f);
    const float* gmp = g_m + part*32;
    const float* bmp = b_m + part*32;
#pragma unroll
    for (int c4 = 0; c4 < 4; c4++){
      bfrag8 st;
#pragma unroll
      for (int e = 0; e < 8; e++){
        int kk = c4*8+e;
        float y = (x[kk]-mu)*rs*gmp[kk] + bmp[kk];
        st[e] = (short)f2bf(y);
      }
      int c = part*4 + c4;
      *reinterpret_cast<bfrag8*>(&Mt[rw*256 + ((c ^ (rw & 7)) << 3)]) = st;
    }
  }
  __syncthreads();

  int w = tid >> 6, lane = tid & 63, i = lane & 15, g = lane >> 4;
  char* EW = smem + 32768 + w*3072;   // per-wave epilogue staging

#pragma unroll 1
  for (int wi = 0; wi < 4; wi++){
    const unsigned short* WTw = WT + wi*65536;
    facc4 acc[4][4];
#pragma unroll
    for (int mt = 0; mt < 4; mt++)
#pragma unroll
      for (int nt = 0; nt < 4; nt++)
        acc[mt][nt] = (facc4){0.f,0.f,0.f,0.f};
#pragma unroll 2
    for (int ks = 0; ks < 8; ks++){
      bfrag8 a[4];
#pragma unroll
      for (int mt = 0; mt < 4; mt++)
        a[mt] = *reinterpret_cast<const bfrag8*>(
            &Mt[(mt*16+i)*256 + (((ks*4+g) ^ (i & 7)) << 3)]);
#pragma unroll
      for (int nt = 0; nt < 4; nt++){
        bfrag8 b = *reinterpret_cast<const bfrag8*>(
            WTw + (w*64 + nt*16 + i)*256 + ks*32 + g*8);
#pragma unroll
        for (int mt = 0; mt < 4; mt++)
          acc[mt][nt] = mm16(a[mt], b, acc[mt][nt]);
      }
    }

    if (wi < 2){
      // ---- q / k : pack (nt,nt+1) pairs -> phys interleave within head ----
      unsigned short* dst = (wi == 0) ? qws : kws;
#pragma unroll 1
      for (int mt = 0; mt < 4; mt++){
#pragma unroll
        for (int r = 0; r < 4; r++){
          *reinterpret_cast<unsigned int*>(EW + (4*g+r)*144 + i*4)
              = pk2(acc[mt][0][r], acc[mt][1][r]);
          *reinterpret_cast<unsigned int*>(EW + (4*g+r)*144 + 64 + i*4)
              = pk2(acc[mt][2][r], acc[mt][3][r]);
        }
#pragma unroll
        for (int rd = 0; rd < 2; rd++){
          int rw2 = rd*8 + (lane >> 3), ch = lane & 7;
          uint4 vv = *reinterpret_cast<uint4*>(EW + rw2*144 + ch*16);
          int ss = s0b + mt*16 + rw2;
          int hh = w*2 + (ch >> 2);
          *reinterpret_cast<uint4*>((char*)dst +
              ((size_t)(((l*8+hh)*256 + ss)*32 + (ch&3)*8))*2) = vv;
        }
      }
    } else if (wi == 2){
      // ---- v : transposed staging -> [l][h][c][s] ----
#pragma unroll 1
      for (int mt = 0; mt < 4; mt++){
#pragma unroll
        for (int nt = 0; nt < 4; nt++){
          uint2 vv;
          vv.x = pk2(acc[mt][nt][0], acc[mt][nt][1]);
          vv.y = pk2(acc[mt][nt][2], acc[mt][nt][3]);
          *reinterpret_cast<uint2*>(EW + (nt*16+i)*48 + g*8) = vv;
        }
        int c = lane;
        int hh = w*2 + (c >> 5), cc = c & 31;
        uint4 a0 = *reinterpret_cast<uint4*>(EW + c*48);
        uint4 a1 = *reinterpret_cast<uint4*>(EW + c*48 + 16);
        size_t eo = ((size_t)((l*8+hh)*32 + cc))*256 + s0b + mt*16;
        *reinterpret_cast<uint4*>((char*)vws + eo*2)      = a0;
        *reinterpret_cast<uint4*>((char*)vws + eo*2 + 16) = a1;
      }
    } else {
      // ---- g : sigmoid(.+bg), packed like q/k, dst [row][n_phys] ----
      float bgv0 = bg[w*64 + i],      bgv1 = bg[w*64 + 16 + i];
      float bgv2 = bg[w*64 + 32 + i], bgv3 = bg[w*64 + 48 + i];
#pragma unroll 1
      for (int mt = 0; mt < 4; mt++){
#pragma unroll
        for (int r = 0; r < 4; r++){
          float t0 = acc[mt][0][r] + bgv0, t1 = acc[mt][1][r] + bgv1;
          float t2 = acc[mt][2][r] + bgv2, t3 = acc[mt][3][r] + bgv3;
          t0 = 1.f/(1.f+__expf(-t0)); t1 = 1.f/(1.f+__expf(-t1));
          t2 = 1.f/(1.f+__expf(-t2)); t3 = 1.f/(1.f+__expf(-t3));
          *reinterpret_cast<unsigned int*>(EW + (4*g+r)*144 + i*4)      = pk2(t0, t1);
          *reinterpret_cast<unsigned int*>(EW + (4*g+r)*144 + 64 + i*4) = pk2(t2, t3);
        }
#pragma unroll
        for (int rd = 0; rd < 2; rd++){
          int rw2 = rd*8 + (lane >> 3), ch = lane & 7;
          uint4 vv = *reinterpret_cast<uint4*>(EW + rw2*144 + ch*16);
          int grow = (s0b + mt*16 + rw2)*256 + l;
          *reinterpret_cast<uint4*>((char*)gws +
              ((size_t)grow*256 + w*64 + ch*8)*2) = vv;
        }
      }
    }
  }
}

// =====================================================================
// kp_bias: LN(z) @ Wb / scale -> bias bf16 [h][s][t]. grid 1024, block 256.
// =====================================================================
__global__ __launch_bounds__(256, 4) void kp_bias(
    const float* __restrict__ z, const float* __restrict__ g_z,
    const float* __restrict__ b_z, const float* __restrict__ Wb,
    unsigned short* __restrict__ biasT){
  __shared__ float WbL[128*8];
  __shared__ float gzL[128], bzL[128];
  int tid = threadIdx.x;
  for (int t = tid; t < 1024; t += 256) WbL[t] = Wb[t];
  if (tid < 128){ gzL[tid] = g_z[tid]; bzL[tid] = b_z[tid]; }
  __syncthreads();

  int grow = blockIdx.x*64 + (tid >> 2);
  int part = tid & 3;
  const float* zr = z + (size_t)grow*128 + part*32;
  float x[32];
  float s1 = 0.f, s2 = 0.f;
#pragma unroll
  for (int j = 0; j < 8; j++){
    float4 v = reinterpret_cast<const float4*>(zr)[j];
    x[j*4+0]=v.x; x[j*4+1]=v.y; x[j*4+2]=v.z; x[j*4+3]=v.w;
    s1 += v.x+v.y+v.z+v.w;
    s2 += v.x*v.x+v.y*v.y+v.z*v.z+v.w*v.w;
  }
  s1 += __shfl_xor(s1,1); s1 += __shfl_xor(s1,2);
  s2 += __shfl_xor(s2,1); s2 += __shfl_xor(s2,2);
  float mu = s1*(1.f/128.f);
  float var = s2*(1.f/128.f) - mu*mu;
  float rs = rsqrtf(var + 1e-5f);
  float acc[8] = {0,0,0,0,0,0,0,0};
#pragma unroll
  for (int zi = 0; zi < 32; zi++){
    int zl = part*32 + zi;
    float v = (x[zi]-mu)*rs*gzL[zl] + bzL[zl];
    float4 wa = *reinterpret_cast<const float4*>(&WbL[zl*8]);
    float4 wb = *reinterpret_cast<const float4*>(&WbL[zl*8+4]);
    acc[0] += v*wa.x; acc[1] += v*wa.y; acc[2] += v*wa.z; acc[3] += v*wa.w;
    acc[4] += v*wb.x; acc[5] += v*wb.y; acc[6] += v*wb.z; acc[7] += v*wb.w;
  }
#pragma unroll
  for (int hh = 0; hh < 8; hh++){
    acc[hh] += __shfl_xor(acc[hh],1);
    acc[hh] += __shfl_xor(acc[hh],2);
  }
  const float ISC = 5.656854249492381f;   // sqrt(32): bias pre-divided by scale
  float v0, v1;
  if      (part == 0){ v0 = acc[0]; v1 = acc[1]; }
  else if (part == 1){ v0 = acc[2]; v1 = acc[3]; }
  else if (part == 2){ v0 = acc[4]; v1 = acc[5]; }
  else               { v0 = acc[6]; v1 = acc[7]; }
  biasT[(2*part)*65536 + grow]   = f2bf(v0*ISC);
  biasT[(2*part+1)*65536 + grow] = f2bf(v1*ISC);
}

// =====================================================================
// kp_attn: per-(l,h). Swapped QK^T (mfma(K,Q) -> S^T), bias as C-init,
// in-lane softmax, P via per-wave swizzled LDS, V^T staged in LDS.
// grid 2048, block 256. No __syncthreads after V staging.
// =====================================================================
__global__ __launch_bounds__(256, 4) void kp_attn(
    const unsigned short* __restrict__ qws, const unsigned short* __restrict__ kws,
    const unsigned short* __restrict__ vws, const unsigned short* __restrict__ biasT,
    unsigned short* __restrict__ ows){
  __shared__ __align__(16) char smem[49152];
  char* VtB = smem;            // 32 x 512B, 16B-xor swizzled
  int tid = threadIdx.x;
  int bid = blockIdx.x;
  int l = bid >> 3, h = bid & 7;
  int base = bid * 8192;       // elems into [l][h][256][32] (and [l][h][32][256])

  // stage V^T ([c][s], true channel order), 16B vector copies
#pragma unroll
  for (int it = 0; it < 4; it++){
    int f = tid + it*256;
    int c = f >> 5, sc = f & 31;
    bfrag8 v = *reinterpret_cast<const bfrag8*>(vws + base + f*8);
    *reinterpret_cast<bfrag8*>(VtB + ((c*512 + sc*16) ^ ((c & 7) << 4))) = v;
  }
  __syncthreads();

  int w = tid >> 6, lane = tid & 63, i = lane & 15, g = lane >> 4;
  char* PtW = smem + 16384 + w*8192;   // per-wave P tile [16 s][256 t]
  const int swzi = (i & 7) << 4;
  const float SC = 0.17677669529663689f;   // 1/sqrt(32)
  const unsigned short* bb = biasT + h*65536;

#pragma unroll 1
  for (int pass = 0; pass < 4; pass++){
    int s0 = (pass*4 + w)*16;
    bfrag8 qf = *reinterpret_cast<const bfrag8*>(qws + base + (s0+i)*32 + g*8);
    facc4 accs[16];
    // S^T = K·Q^T with C-init = bias/scale  (lane: s = s0+i, t = tt*16+4g+r)
#pragma unroll
    for (int tt = 0; tt < 16; tt++){
      bfrag8 kf = *reinterpret_cast<const bfrag8*>(kws + base + (tt*16+i)*32 + g*8);
      uint2 bv = *reinterpret_cast<const uint2*>(bb + (s0+i)*256 + tt*16 + 4*g);
      facc4 c;
      c[0] = bf2f((unsigned short)(bv.x));
      c[1] = bf2f((unsigned short)(bv.x >> 16));
      c[2] = bf2f((unsigned short)(bv.y));
      c[3] = bf2f((unsigned short)(bv.y >> 16));
      accs[tt] = mm16(kf, qf, c);
    }
    // in-lane softmax over 64 t-values + 2 shuffles across g
    float mx = -3.0e38f;
#pragma unroll
    for (int tt = 0; tt < 16; tt++){
      float m2 = fmaxf(fmaxf(accs[tt][0], accs[tt][1]),
                       fmaxf(accs[tt][2], accs[tt][3]));
      mx = fmaxf(mx, m2);
    }
    mx = fmaxf(mx, __shfl_xor(mx, 16));
    mx = fmaxf(mx, __shfl_xor(mx, 32));
    float sum = 0.f;
#pragma unroll
    for (int tt = 0; tt < 16; tt++){
      float p0 = __expf((accs[tt][0]-mx)*SC);
      float p1 = __expf((accs[tt][1]-mx)*SC);
      float p2 = __expf((accs[tt][2]-mx)*SC);
      float p3 = __expf((accs[tt][3]-mx)*SC);
      sum += (p0+p1) + (p2+p3);
      uint2 pv; pv.x = pk2(p0,p1); pv.y = pk2(p2,p3);
      *reinterpret_cast<uint2*>(PtW + ((i*512 + tt*32 + g*8) ^ swzi)) = pv;
    }
    sum += __shfl_xor(sum, 16);
    sum += __shfl_xor(sum, 32);
    float invRow = 1.0f / sum;
    // PV
    facc4 o0 = (facc4){0.f,0.f,0.f,0.f}, o1 = (facc4){0.f,0.f,0.f,0.f};
#pragma unroll 2
    for (int kt = 0; kt < 8; kt++){
      bfrag8 pa = *reinterpret_cast<const bfrag8*>(
          PtW + ((i*512 + kt*64 + g*16) ^ swzi));
      bfrag8 b0 = *reinterpret_cast<const bfrag8*>(
          VtB + ((i*512 + kt*64 + g*16) ^ ((i & 7) << 4)));
      bfrag8 b1 = *reinterpret_cast<const bfrag8*>(
          VtB + (((16+i)*512 + kt*64 + g*16) ^ ((i & 7) << 4)));
      o0 = mm16(pa, b0, o0);
      o1 = mm16(pa, b1, o1);
    }
    // scale by 1/rowsum (shuffle: row 4g+r lives in lane (g,i=4g+r)), pack, stage
#pragma unroll
    for (int r = 0; r < 4; r++){
      float invr = __shfl(invRow, (g << 4) + (g << 2) + r);
      *reinterpret_cast<unsigned int*>(PtW + (4*g+r)*80 + i*4)
          = pk2(o0[r]*invr, o1[r]*invr);
    }
    {
      int row = lane >> 2, ch = lane & 3;
      uint4 ov = *reinterpret_cast<uint4*>(PtW + row*80 + ch*16);
      *reinterpret_cast<uint4*>((char*)ows +
          (((size_t)(s0+row)*256 + l)*256 + h*32 + ch*8)*2) = ov;
    }
  }
}

// =====================================================================
// kp_out: out = (g .* o) @ Wo + bo. grid 1024, block 256.
// =====================================================================
__global__ __launch_bounds__(256, 4) void kp_out(
    const unsigned short* __restrict__ gws, const unsigned short* __restrict__ ows,
    const unsigned short* __restrict__ WT, const float* __restrict__ bo,
    float* __restrict__ out){
  __shared__ __align__(16) unsigned short Mt[64*256];
  int tid = threadIdx.x;
  int r0  = blockIdx.x * 64;
  {
    int rw = tid >> 2, part = tid & 3;
    int grow = r0 + rw;
    const unsigned short* gp = gws + (size_t)grow*256 + part*64;
    const unsigned short* op = ows + (size_t)grow*256 + part*64;
#pragma unroll
    for (int c8 = 0; c8 < 8; c8++){
      bfrag8 gv = *reinterpret_cast<const bfrag8*>(gp + c8*8);
      bfrag8 ov = *reinterpret_cast<const bfrag8*>(op + c8*8);
      bfrag8 st;
#pragma unroll
      for (int e = 0; e < 8; e++){
        float y = bf2f((unsigned short)gv[e]) * bf2f((unsigned short)ov[e]);
        st[e] = (short)f2bf(y);
      }
      int c = part*8 + c8;
      *reinterpret_cast<bfrag8*>(&Mt[rw*256 + ((c ^ (rw & 7)) << 3)]) = st;
    }
  }
  __syncthreads();

  int w = tid >> 6, lane = tid & 63, i = lane & 15, g = lane >> 4;
  const unsigned short* WTw = WT + 4*65536;   // Wo^T (k-rows pi-permuted)
  facc4 acc[4][4];
#pragma unroll
  for (int mt = 0; mt < 4; mt++)
#pragma unroll
    for (int nt = 0; nt < 4; nt++)
      acc[mt][nt] = (facc4){0.f,0.f,0.f,0.f};
#pragma unroll 2
  for (int ks = 0; ks < 8; ks++){
    bfrag8 a[4];
#pragma unroll
    for (int mt = 0; mt < 4; mt++)
      a[mt] = *reinterpret_cast<const bfrag8*>(
          &Mt[(mt*16+i)*256 + (((ks*4+g) ^ (i & 7)) << 3)]);
#pragma unroll
    for (int nt = 0; nt < 4; nt++){
      bfrag8 b = *reinterpret_cast<const bfrag8*>(
          WTw + (w*64 + nt*16 + i)*256 + ks*32 + g*8);
#pragma unroll
      for (int mt = 0; mt < 4; mt++)
        acc[mt][nt] = mm16(a[mt], b, acc[mt][nt]);
    }
  }
#pragma unroll
  for (int nt = 0; nt < 4; nt++){
    int col = w*64 + nt*16 + i;
    float bov = bo[col];
#pragma unroll
    for (int mt = 0; mt < 4; mt++){
#pragma unroll
      for (int r = 0; r < 4; r++){
        int grow = r0 + mt*16 + 4*g + r;
        out[(size_t)grow*256 + col] = acc[mt][nt][r] + bov;
      }
    }
  }
}

// =====================================================================
extern "C" void kernel_launch(void* const* d_in, const int* in_sizes, int n_in,
                              void* d_out, int out_size, void* d_ws, size_t ws_size,
                              hipStream_t stream) {
  (void)in_sizes; (void)n_in; (void)out_size; (void)ws_size;
  const float* m   = (const float*)d_in[0];
  const float* z   = (const float*)d_in[1];
  const float* g_m = (const float*)d_in[2];
  const float* b_m = (const float*)d_in[3];
  const float* g_z = (const float*)d_in[4];
  const float* b_z = (const float*)d_in[5];
  const float* Wq  = (const float*)d_in[6];
  const float* Wk  = (const float*)d_in[7];
  const float* Wv  = (const float*)d_in[8];
  const float* Wb  = (const float*)d_in[9];
  const float* Wg  = (const float*)d_in[10];
  const float* bg  = (const float*)d_in[11];
  const float* Wo  = (const float*)d_in[12];
  const float* bo  = (const float*)d_in[13];

  char* ws = (char*)d_ws;
  unsigned short* qws    = (unsigned short*)(ws);                 // 32 MB [l][h][s][c_phys]
  unsigned short* kws    = (unsigned short*)(ws + 33554432);      // 32 MB [l][h][s][c_phys]
  unsigned short* vws    = (unsigned short*)(ws + 67108864);      // 32 MB [l][h][c][s]
  unsigned short* gws    = (unsigned short*)(ws + 100663296);     // 32 MB [row][n_phys]
  unsigned short* ows    = (unsigned short*)(ws + 134217728);     // 32 MB [row][n_phys]
  unsigned short* biasT  = (unsigned short*)(ws + 167772160);     // 1 MB  [h][s][t]
  unsigned short* WT     = (unsigned short*)(ws + 168820736);     // 640 KB [w][n][k]
  float* out = (float*)d_out;

  kp_prep<<<dim3(1280), dim3(256), 0, stream>>>(Wq, Wk, Wv, Wg, Wo, WT);
  kp_proj<<<dim3(1024), dim3(256), 0, stream>>>(m, g_m, b_m, WT, bg, qws, kws, vws, gws);
  kp_bias<<<dim3(1024), dim3(256), 0, stream>>>(z, g_z, b_z, Wb, biasT);
  kp_attn<<<dim3(2048), dim3(256), 0, stream>>>(qws, kws, vws, biasT, ows);
  kp_out <<<dim3(1024), dim3(256), 0, stream>>>(gws, ows, WT, bo, out);
}

// Round 3
// 379.861 us; speedup vs baseline: 1.3917x; 1.2421x over previous
//
#include <hip/hip_runtime.h>
#include <cstdint>
#include <cstddef>

using bfrag8 = __attribute__((ext_vector_type(8))) short;  // 8 bf16
using facc4  = __attribute__((ext_vector_type(4))) float;  // MFMA acc

__device__ __forceinline__ unsigned short f2bf(float f){
  unsigned int u = __builtin_bit_cast(unsigned int, f);
  u += 0x7fffu + ((u >> 16) & 1u);          // RNE
  return (unsigned short)(u >> 16);
}
__device__ __forceinline__ float bf2f(unsigned short h){
  unsigned int u = ((unsigned int)h) << 16;
  return __builtin_bit_cast(float, u);
}
__device__ __forceinline__ unsigned int pk2(float a, float b){
  return (unsigned int)f2bf(a) | ((unsigned int)f2bf(b) << 16);
}
__device__ __forceinline__ facc4 mm16(bfrag8 a, bfrag8 b, facc4 c){
  return __builtin_amdgcn_mfma_f32_16x16x32_bf16(a, b, c, 0, 0, 0);
}

// =====================================================================
// kp_prep: W[k][n] fp32 -> WT[w][n][k] bf16.
//  w==4 (Wo): K index permuted by pi (phys channel order of o/g).
//  w==3 (Wg): N index permuted by pi (so g cols align with o phys order).
//  pi within a 32-chunk: c = 16a+b -> 2b+a.
// =====================================================================
__global__ __launch_bounds__(256) void kp_prep(
    const float* __restrict__ Wq, const float* __restrict__ Wk,
    const float* __restrict__ Wv, const float* __restrict__ Wg,
    const float* __restrict__ Wo, unsigned short* __restrict__ WT){
  int b = blockIdx.x;
  int w = b >> 8;          // which weight
  int k = b & 255;         // source row (input dim)
  int n = threadIdx.x;     // source col (output dim)
  const float* W = (w==0)?Wq:(w==1)?Wk:(w==2)?Wv:(w==3)?Wg:Wo;
  int kk = k, nn = n;
  if (w == 4) kk = (k & ~31) | ((k & 15) << 1) | ((k >> 4) & 1);
  if (w == 3) nn = (n & ~31) | ((n & 15) << 1) | ((n >> 4) & 1);
  WT[w*65536 + nn*256 + kk] = f2bf(W[k*256 + n]);
}

// =====================================================================
// kp_ln: LN(m) fp32 [s*256+l][c] -> mln bf16 [l][s][c]. grid 2048, blk 256.
// 8 threads/row, 32 rows/block; LDS repack so global stores are 128B runs.
// =====================================================================
__global__ __launch_bounds__(256) void kp_ln(
    const float* __restrict__ m, const float* __restrict__ g_m,
    const float* __restrict__ b_m, unsigned short* __restrict__ mln){
  __shared__ __align__(16) unsigned short T[32*256];
  int tid = threadIdx.x;
  int r0 = blockIdx.x * 32;
  int rowL = tid >> 3, part = tid & 7;
  int rowg = r0 + rowL;
  const float* mrow = m + (size_t)rowg*256 + part*32;
  float x[32];
  float s1 = 0.f, s2 = 0.f;
#pragma unroll
  for (int j = 0; j < 8; j++){
    float4 v = reinterpret_cast<const float4*>(mrow)[j];
    x[j*4+0]=v.x; x[j*4+1]=v.y; x[j*4+2]=v.z; x[j*4+3]=v.w;
    s1 += v.x+v.y+v.z+v.w;
    s2 += v.x*v.x+v.y*v.y+v.z*v.z+v.w*v.w;
  }
  s1 += __shfl_xor(s1,1); s1 += __shfl_xor(s1,2); s1 += __shfl_xor(s1,4);
  s2 += __shfl_xor(s2,1); s2 += __shfl_xor(s2,2); s2 += __shfl_xor(s2,4);
  float mu = s1*(1.f/256.f);
  float var = s2*(1.f/256.f) - mu*mu;
  float rs = rsqrtf(var + 1e-5f);
  const float* gmp = g_m + part*32;
  const float* bmp = b_m + part*32;
#pragma unroll
  for (int c4 = 0; c4 < 4; c4++){
    bfrag8 st;
#pragma unroll
    for (int e = 0; e < 8; e++){
      int kk = c4*8+e;
      float y = (x[kk]-mu)*rs*gmp[kk] + bmp[kk];
      st[e] = (short)f2bf(y);
    }
    *reinterpret_cast<bfrag8*>(&T[rowL*256 + part*32 + c4*8]) = st;
  }
  __syncthreads();
  int s = rowg >> 8, l = rowg & 255;
  unsigned short* dst = mln + ((size_t)(l*256 + s))*256;
#pragma unroll
  for (int j = 0; j < 4; j++){
    bfrag8 v = *reinterpret_cast<const bfrag8*>(&T[rowL*256 + j*64 + part*8]);
    *reinterpret_cast<bfrag8*>(dst + j*64 + part*8) = v;
  }
}

// =====================================================================
// kp_bias: LN(z) @ Wb / scale -> bias bf16 [h][s][t]. grid 1024, block 256.
// =====================================================================
__global__ __launch_bounds__(256, 4) void kp_bias(
    const float* __restrict__ z, const float* __restrict__ g_z,
    const float* __restrict__ b_z, const float* __restrict__ Wb,
    unsigned short* __restrict__ biasT){
  __shared__ float WbL[128*8];
  __shared__ float gzL[128], bzL[128];
  int tid = threadIdx.x;
  for (int t = tid; t < 1024; t += 256) WbL[t] = Wb[t];
  if (tid < 128){ gzL[tid] = g_z[tid]; bzL[tid] = b_z[tid]; }
  __syncthreads();

  int grow = blockIdx.x*64 + (tid >> 2);
  int part = tid & 3;
  const float* zr = z + (size_t)grow*128 + part*32;
  float x[32];
  float s1 = 0.f, s2 = 0.f;
#pragma unroll
  for (int j = 0; j < 8; j++){
    float4 v = reinterpret_cast<const float4*>(zr)[j];
    x[j*4+0]=v.x; x[j*4+1]=v.y; x[j*4+2]=v.z; x[j*4+3]=v.w;
    s1 += v.x+v.y+v.z+v.w;
    s2 += v.x*v.x+v.y*v.y+v.z*v.z+v.w*v.w;
  }
  s1 += __shfl_xor(s1,1); s1 += __shfl_xor(s1,2);
  s2 += __shfl_xor(s2,1); s2 += __shfl_xor(s2,2);
  float mu = s1*(1.f/128.f);
  float var = s2*(1.f/128.f) - mu*mu;
  float rs = rsqrtf(var + 1e-5f);
  float acc[8] = {0,0,0,0,0,0,0,0};
#pragma unroll
  for (int zi = 0; zi < 32; zi++){
    int zl = part*32 + zi;
    float v = (x[zi]-mu)*rs*gzL[zl] + bzL[zl];
    float4 wa = *reinterpret_cast<const float4*>(&WbL[zl*8]);
    float4 wb = *reinterpret_cast<const float4*>(&WbL[zl*8+4]);
    acc[0] += v*wa.x; acc[1] += v*wa.y; acc[2] += v*wa.z; acc[3] += v*wa.w;
    acc[4] += v*wb.x; acc[5] += v*wb.y; acc[6] += v*wb.z; acc[7] += v*wb.w;
  }
#pragma unroll
  for (int hh = 0; hh < 8; hh++){
    acc[hh] += __shfl_xor(acc[hh],1);
    acc[hh] += __shfl_xor(acc[hh],2);
  }
  const float ISC = 5.656854249492381f;   // sqrt(32): bias pre-divided by scale
  float v0, v1;
  if      (part == 0){ v0 = acc[0]; v1 = acc[1]; }
  else if (part == 1){ v0 = acc[2]; v1 = acc[3]; }
  else if (part == 2){ v0 = acc[4]; v1 = acc[5]; }
  else               { v0 = acc[6]; v1 = acc[7]; }
  biasT[(2*part)*65536 + grow]   = f2bf(v0*ISC);
  biasT[(2*part+1)*65536 + grow] = f2bf(v1*ISC);
}

// =====================================================================
// kp_attn2: per-(l,h) fused projection + attention. grid 2048, block 256.
// blockIdx decode keeps all 8 same-l blocks on one XCD (bid%8 round-robin).
// LDS: qT 16K | kT 16K | vT 16K | panels/P 32K = 80 KB -> 2 blocks/CU.
// =====================================================================
__global__ __launch_bounds__(256, 2) void kp_attn2(
    const unsigned short* __restrict__ mln, const unsigned short* __restrict__ WT,
    const unsigned short* __restrict__ biasT, unsigned short* __restrict__ ows){
  __shared__ __align__(16) char smem[81920];
  unsigned short* qT = (unsigned short*)smem;          // [256 s][32 p] rows 64B
  unsigned short* kT = (unsigned short*)(smem+16384);  // [256 t][32 p]
  char* vTB = smem + 32768;                            // [32 c][256 t] rows 512B
  char* PAN = smem + 49152;                            // panels, later P tiles

  int tid = threadIdx.x;
  int bid = blockIdx.x;
  int slot = bid & 7, idx = bid >> 3;
  int h = idx & 7;
  int l = slot + ((idx >> 3) << 3);

  int w = tid >> 6, lane = tid & 63, i = lane & 15, g = lane >> 4;

  // ---------------- projection: q,k,v for this (l,h) ----------------
  const unsigned short* WQ = WT + 0*65536 + (h*32)*256;
  const unsigned short* WK = WT + 1*65536 + (h*32)*256;
  const unsigned short* WV = WT + 2*65536 + (h*32)*256;
  facc4 aq[4][2], ak[4][2], av[4][2];
#pragma unroll
  for (int mt = 0; mt < 4; mt++)
#pragma unroll
    for (int nt = 0; nt < 2; nt++){
      aq[mt][nt] = (facc4){0.f,0.f,0.f,0.f};
      ak[mt][nt] = (facc4){0.f,0.f,0.f,0.f};
      av[mt][nt] = (facc4){0.f,0.f,0.f,0.f};
    }

#pragma unroll 1
  for (int kp = 0; kp < 4; kp++){
    __syncthreads();
    // stage panel mln[l][0..255][kp*64..+63] -> PAN [256 s][64 k] swizzled
#pragma unroll
    for (int it = 0; it < 8; it++){
      int cid = it*256 + tid;
      int s = cid >> 3, kc = cid & 7;
      bfrag8 v = *reinterpret_cast<const bfrag8*>(
          mln + ((size_t)(l*256 + s))*256 + kp*64 + kc*8);
      *reinterpret_cast<bfrag8*>(PAN + s*128 + ((kc ^ (s & 7)) << 4)) = v;
    }
    __syncthreads();
#pragma unroll
    for (int ksub = 0; ksub < 2; ksub++){
      int kglob = kp*64 + ksub*32;
      bfrag8 bq0 = *reinterpret_cast<const bfrag8*>(WQ + i*256        + kglob + g*8);
      bfrag8 bq1 = *reinterpret_cast<const bfrag8*>(WQ + (16+i)*256   + kglob + g*8);
      bfrag8 bk0 = *reinterpret_cast<const bfrag8*>(WK + i*256        + kglob + g*8);
      bfrag8 bk1 = *reinterpret_cast<const bfrag8*>(WK + (16+i)*256   + kglob + g*8);
      bfrag8 bv0 = *reinterpret_cast<const bfrag8*>(WV + i*256        + kglob + g*8);
      bfrag8 bv1 = *reinterpret_cast<const bfrag8*>(WV + (16+i)*256   + kglob + g*8);
#pragma unroll
      for (int mt = 0; mt < 4; mt++){
        int row = w*64 + mt*16 + i;
        bfrag8 a = *reinterpret_cast<const bfrag8*>(
            PAN + row*128 + ((((ksub<<2)+g) ^ (row & 7)) << 4));
        aq[mt][0] = mm16(a, bq0, aq[mt][0]);
        aq[mt][1] = mm16(a, bq1, aq[mt][1]);
        ak[mt][0] = mm16(a, bk0, ak[mt][0]);
        ak[mt][1] = mm16(a, bk1, ak[mt][1]);
        av[mt][0] = mm16(a, bv0, av[mt][0]);
        av[mt][1] = mm16(a, bv1, av[mt][1]);
      }
    }
  }

  // epilogue to LDS tiles. q/k: p = 2i+nt pairs, rows 64B, swz ^((row>>1)&3).
#pragma unroll
  for (int mt = 0; mt < 4; mt++){
#pragma unroll
    for (int r = 0; r < 4; r++){
      int s = w*64 + mt*16 + 4*g + r;
      int sw = (((i >> 2) ^ ((s >> 1) & 3)) << 4) + (i & 3)*4;
      *reinterpret_cast<unsigned int*>((char*)qT + s*64 + sw)
          = pk2(aq[mt][0][r], aq[mt][1][r]);
      *reinterpret_cast<unsigned int*>((char*)kT + s*64 + sw)
          = pk2(ak[mt][0][r], ak[mt][1][r]);
    }
    // v: true-c rows [c][256 t], uint2 (4 t), swz chunk ^ (c&7)
#pragma unroll
    for (int nt = 0; nt < 2; nt++){
      int c = nt*16 + i;
      int t0 = w*64 + mt*16 + 4*g;
      uint2 vv;
      vv.x = pk2(av[mt][nt][0], av[mt][nt][1]);
      vv.y = pk2(av[mt][nt][2], av[mt][nt][3]);
      int tc = t0 >> 3;
      int half = (t0 >> 2) & 1;
      *reinterpret_cast<uint2*>(vTB + c*512 + ((tc ^ (c & 7)) << 4) + half*8) = vv;
    }
  }
  __syncthreads();

  // ---------------- attention (barrier-free; per-wave state) ----------------
  char* PtW = PAN + w*8192;     // [16 s][256 t] bf16, per-wave
  const int swzi = (i & 7) << 4;
  const float SC = 0.17677669529663689f;   // 1/sqrt(32)
  const unsigned short* bb = biasT + h*65536;

#pragma unroll 1
  for (int pass = 0; pass < 4; pass++){
    int s0 = (pass*4 + w)*16;
    int qs = s0 + i;
    bfrag8 qf = *reinterpret_cast<const bfrag8*>(
        (char*)qT + qs*64 + ((g ^ ((qs >> 1) & 3)) << 4));
    facc4 accs[16];
#pragma unroll
    for (int tt = 0; tt < 16; tt++){
      int t = tt*16 + i;
      bfrag8 kf = *reinterpret_cast<const bfrag8*>(
          (char*)kT + t*64 + ((g ^ ((t >> 1) & 3)) << 4));
      uint2 bv = *reinterpret_cast<const uint2*>(bb + (s0+i)*256 + tt*16 + 4*g);
      facc4 c;
      c[0] = bf2f((unsigned short)(bv.x));
      c[1] = bf2f((unsigned short)(bv.x >> 16));
      c[2] = bf2f((unsigned short)(bv.y));
      c[3] = bf2f((unsigned short)(bv.y >> 16));
      accs[tt] = mm16(kf, qf, c);
    }
    float mx = -3.0e38f;
#pragma unroll
    for (int tt = 0; tt < 16; tt++){
      float m2 = fmaxf(fmaxf(accs[tt][0], accs[tt][1]),
                       fmaxf(accs[tt][2], accs[tt][3]));
      mx = fmaxf(mx, m2);
    }
    mx = fmaxf(mx, __shfl_xor(mx, 16));
    mx = fmaxf(mx, __shfl_xor(mx, 32));
    float sum = 0.f;
#pragma unroll
    for (int tt = 0; tt < 16; tt++){
      float p0 = __expf((accs[tt][0]-mx)*SC);
      float p1 = __expf((accs[tt][1]-mx)*SC);
      float p2 = __expf((accs[tt][2]-mx)*SC);
      float p3 = __expf((accs[tt][3]-mx)*SC);
      sum += (p0+p1) + (p2+p3);
      uint2 pv; pv.x = pk2(p0,p1); pv.y = pk2(p2,p3);
      *reinterpret_cast<uint2*>(PtW + ((i*512 + tt*32 + g*8) ^ swzi)) = pv;
    }
    sum += __shfl_xor(sum, 16);
    sum += __shfl_xor(sum, 32);
    float invRow = 1.0f / sum;
    facc4 o0 = (facc4){0.f,0.f,0.f,0.f}, o1 = (facc4){0.f,0.f,0.f,0.f};
#pragma unroll 2
    for (int kt = 0; kt < 8; kt++){
      bfrag8 pa = *reinterpret_cast<const bfrag8*>(
          PtW + ((i*512 + kt*64 + g*16) ^ swzi));
      int tc = kt*4 + g;
      bfrag8 b0 = *reinterpret_cast<const bfrag8*>(
          vTB + i*512 + ((tc ^ (i & 7)) << 4));
      bfrag8 b1 = *reinterpret_cast<const bfrag8*>(
          vTB + (16+i)*512 + ((tc ^ (i & 7)) << 4));
      o0 = mm16(pa, b0, o0);
      o1 = mm16(pa, b1, o1);
    }
    // stage o (phys order via pk2(o0,o1) = (c, c+16) interleave), store 64B runs
#pragma unroll
    for (int r = 0; r < 4; r++){
      float invr = __shfl(invRow, (g << 4) + (g << 2) + r);
      *reinterpret_cast<unsigned int*>(PtW + (4*g+r)*80 + i*4)
          = pk2(o0[r]*invr, o1[r]*invr);
    }
    {
      int row = lane >> 2, ch = lane & 3;
      uint4 ov = *reinterpret_cast<uint4*>(PtW + row*80 + ch*16);
      *reinterpret_cast<uint4*>((char*)ows +
          (((size_t)(s0+row)*256 + l)*256 + h*32 + ch*8)*2) = ov;
    }
  }
}

// =====================================================================
// kp_out2: out = (sigmoid(mln@Wg+bg) .* o) @ Wo + bo. grid 1024, block 256.
// Fuses the g projection. LDS: Mt 32K + Ot 32K = 64 KB.
// =====================================================================
__global__ __launch_bounds__(256, 2) void kp_out2(
    const unsigned short* __restrict__ mln, const unsigned short* __restrict__ ows,
    const unsigned short* __restrict__ WT, const float* __restrict__ bg,
    const float* __restrict__ bo, float* __restrict__ out){
  __shared__ __align__(16) char smem[65536];
  char* Mt = smem;            // [64 rows][256 c] bf16, swizzled
  char* Ot = smem + 32768;    // [64 rows][256 p] bf16, swizzled
  int tid = threadIdx.x;
  int r0  = blockIdx.x * 64;
  int s   = r0 >> 8, l0 = r0 & 255;

#pragma unroll
  for (int it = 0; it < 8; it++){
    int cid = it*256 + tid;
    int rowL = cid >> 5, ch = cid & 31;
    bfrag8 a = *reinterpret_cast<const bfrag8*>(
        mln + ((size_t)((l0+rowL)*256 + s))*256 + ch*8);
    *reinterpret_cast<bfrag8*>(Mt + rowL*512 + ((ch ^ (rowL & 7)) << 4)) = a;
    bfrag8 b = *reinterpret_cast<const bfrag8*>(
        ows + (size_t)(r0+rowL)*256 + ch*8);
    *reinterpret_cast<bfrag8*>(Ot + rowL*512 + ((ch ^ (rowL & 7)) << 4)) = b;
  }
  __syncthreads();

  int w = tid >> 6, lane = tid & 63, i = lane & 15, g = lane >> 4;
  const unsigned short* WTg = WT + 3*65536;   // rows = p-permuted g cols
  const unsigned short* WTo = WT + 4*65536;   // [n][k_p]

  // ---- GEMM1: g = mln @ Wg (cols in phys order) ----
  facc4 acc[4][4];
#pragma unroll
  for (int mt = 0; mt < 4; mt++)
#pragma unroll
    for (int nt = 0; nt < 4; nt++)
      acc[mt][nt] = (facc4){0.f,0.f,0.f,0.f};
#pragma unroll 2
  for (int ks = 0; ks < 8; ks++){
    bfrag8 a[4];
#pragma unroll
    for (int mt = 0; mt < 4; mt++){
      int row = mt*16 + i;
      a[mt] = *reinterpret_cast<const bfrag8*>(
          Mt + row*512 + ((((ks*4+g) ^ (row & 7))) << 4));
    }
#pragma unroll
    for (int nt = 0; nt < 4; nt++){
      bfrag8 b = *reinterpret_cast<const bfrag8*>(
          WTg + (w*64 + nt*16 + i)*256 + ks*32 + g*8);
#pragma unroll
      for (int mt = 0; mt < 4; mt++)
        acc[mt][nt] = mm16(a[mt], b, acc[mt][nt]);
    }
  }

  // ---- sigmoid, multiply by o, write product into Mt (A for GEMM2) ----
  float bgv[4];
#pragma unroll
  for (int nt = 0; nt < 4; nt++){
    int p = w*64 + nt*16 + i;
    int ntr = (p & ~31) | ((p & 1) << 4) | ((p & 31) >> 1);   // pi^-1
    bgv[nt] = bg[ntr];
  }
  __syncthreads();   // all waves done reading Mt
#pragma unroll
  for (int mt = 0; mt < 4; mt++){
#pragma unroll
    for (int nt = 0; nt < 4; nt++){
      int p = w*64 + nt*16 + i;
#pragma unroll
      for (int r = 0; r < 4; r++){
        int row = mt*16 + 4*g + r;
        int off = row*512 + ((((p>>3) ^ (row & 7))) << 4) + (p & 7)*2;
        float ov = bf2f(*reinterpret_cast<const unsigned short*>(Ot + off));
        float t = acc[mt][nt][r] + bgv[nt];
        float gg = 1.0f / (1.0f + __expf(-t));
        *reinterpret_cast<unsigned short*>(Mt + off) = f2bf(gg * ov);
      }
    }
  }
  __syncthreads();

  // ---- GEMM2: (g.*o) @ Wo + bo ----
  facc4 acc2[4][4];
#pragma unroll
  for (int mt = 0; mt < 4; mt++)
#pragma unroll
    for (int nt = 0; nt < 4; nt++)
      acc2[mt][nt] = (facc4){0.f,0.f,0.f,0.f};
#pragma unroll 2
  for (int ks = 0; ks < 8; ks++){
    bfrag8 a[4];
#pragma unroll
    for (int mt = 0; mt < 4; mt++){
      int row = mt*16 + i;
      a[mt] = *reinterpret_cast<const bfrag8*>(
          Mt + row*512 + ((((ks*4+g) ^ (row & 7))) << 4));
    }
#pragma unroll
    for (int nt = 0; nt < 4; nt++){
      bfrag8 b = *reinterpret_cast<const bfrag8*>(
          WTo + (w*64 + nt*16 + i)*256 + ks*32 + g*8);
#pragma unroll
      for (int mt = 0; mt < 4; mt++)
        acc2[mt][nt] = mm16(a[mt], b, acc2[mt][nt]);
    }
  }
#pragma unroll
  for (int nt = 0; nt < 4; nt++){
    int col = w*64 + nt*16 + i;
    float bov = bo[col];
#pragma unroll
    for (int mt = 0; mt < 4; mt++){
#pragma unroll
      for (int r = 0; r < 4; r++){
        int grow = r0 + mt*16 + 4*g + r;
        out[(size_t)grow*256 + col] = acc2[mt][nt][r] + bov;
      }
    }
  }
}

// =====================================================================
extern "C" void kernel_launch(void* const* d_in, const int* in_sizes, int n_in,
                              void* d_out, int out_size, void* d_ws, size_t ws_size,
                              hipStream_t stream) {
  (void)in_sizes; (void)n_in; (void)out_size; (void)ws_size;
  const float* m   = (const float*)d_in[0];
  const float* z   = (const float*)d_in[1];
  const float* g_m = (const float*)d_in[2];
  const float* b_m = (const float*)d_in[3];
  const float* g_z = (const float*)d_in[4];
  const float* b_z = (const float*)d_in[5];
  const float* Wq  = (const float*)d_in[6];
  const float* Wk  = (const float*)d_in[7];
  const float* Wv  = (const float*)d_in[8];
  const float* Wb  = (const float*)d_in[9];
  const float* Wg  = (const float*)d_in[10];
  const float* bg  = (const float*)d_in[11];
  const float* Wo  = (const float*)d_in[12];
  const float* bo  = (const float*)d_in[13];

  char* ws = (char*)d_ws;
  unsigned short* mln    = (unsigned short*)(ws);                 // 32 MB [l][s][c]
  unsigned short* ows    = (unsigned short*)(ws + 33554432);      // 32 MB [s*256+l][p]
  unsigned short* biasT  = (unsigned short*)(ws + 67108864);      // 1 MB  [h][s][t]
  unsigned short* WT     = (unsigned short*)(ws + 68157440);      // 640 KB [w][n][k]
  float* out = (float*)d_out;

  kp_prep <<<dim3(1280), dim3(256), 0, stream>>>(Wq, Wk, Wv, Wg, Wo, WT);
  kp_ln   <<<dim3(2048), dim3(256), 0, stream>>>(m, g_m, b_m, mln);
  kp_bias <<<dim3(1024), dim3(256), 0, stream>>>(z, g_z, b_z, Wb, biasT);
  kp_attn2<<<dim3(2048), dim3(256), 0, stream>>>(mln, WT, biasT, ows);
  kp_out2 <<<dim3(1024), dim3(256), 0, stream>>>(mln, ows, WT, bg, bo, out);
}